// Round 3
// baseline (5314.809 us; speedup 1.0000x reference)
//
#include <hip/hip_runtime.h>
#include <hip/hip_cooperative_groups.h>
#include <math.h>

namespace cg = cooperative_groups;

// Sinkhorn loss, B=8, S=2048, P=1024, D=2, eps=0.01, 50 iters.
// Base-2 scaled potentials: F2 = f/(eps*ln2), G2 = g/(eps*ln2).
//   v2(s,p) = -K*C(s,p) + G2[p],  K = 100*log2(e)
// Row-const -K*x2 folds out of the LSE; q = pot - K*sqnorm staged in LDS.
// Persistent cooperative kernel: 512 blocks x 256 thr (2 blocks/CU, exactly
// co-resident), grid.sync() between phases -> one dispatch for everything.

#define BB 8
#define SS 2048
#define PP 1024
#define NEG_INF -1e9f
#define LOG2S 11.0f
#define ITERS 50
#define K2E 144.269504088896f   /* 100*log2(e) */
#define TWOK 288.539008177792f  /* 200*log2(e) */

__device__ __forceinline__ float fexp2(float x) { return __builtin_amdgcn_exp2f(x); }
__device__ __forceinline__ float flog2(float x) { return __builtin_amdgcn_logf(x); }

// ---- phase bodies (shared by cooperative kernel and fallback kernels) ----

// f: block bid handles 32 rows; wave = 8 rows x 8 chunks, 128 cols/lane.
__device__ __forceinline__ void f_body(int bid, int t, float4* sh,
    const float4* __restrict__ ypackG, const float* __restrict__ preds,
    float4* __restrict__ xpackF) {
  int bb = bid >> 6;  // 64 blocks per batch
  const float4* ysrc = ypackG + (bb << 10);
#pragma unroll
  for (int k = 0; k < 4; ++k) {
    int e = t + (k << 8);
    float4 y = ysrc[e];
    sh[e + (e >> 7)] = make_float4(y.x, y.y, fmaf(-K2E, y.z, y.w), 0.0f);
  }
  __syncthreads();
  int w = t >> 6, lane = t & 63;
  int r = lane & 7, chunk = lane >> 3;
  int row = (bid << 5) + (w << 3) + r;
  float2 x = ((const float2*)preds)[row];
  float x2 = x.x * x.x + x.y * x.y;
  float kx0 = TWOK * x.x, kx1 = TWOK * x.y;
  const float4* cb = sh + chunk * 129;
  float u[128];
  float m0 = -3.4e38f, m1 = m0, m2 = m0, m3 = m0;
#pragma unroll
  for (int i = 0; i < 128; i += 4) {
    float4 a0 = cb[i], a1 = cb[i + 1], a2 = cb[i + 2], a3 = cb[i + 3];
    float u0 = fmaf(kx0, a0.x, fmaf(kx1, a0.y, a0.z));
    float u1 = fmaf(kx0, a1.x, fmaf(kx1, a1.y, a1.z));
    float u2 = fmaf(kx0, a2.x, fmaf(kx1, a2.y, a2.z));
    float u3 = fmaf(kx0, a3.x, fmaf(kx1, a3.y, a3.z));
    u[i] = u0; u[i + 1] = u1; u[i + 2] = u2; u[i + 3] = u3;
    m0 = fmaxf(m0, u0); m1 = fmaxf(m1, u1);
    m2 = fmaxf(m2, u2); m3 = fmaxf(m3, u3);
  }
  float m = fmaxf(fmaxf(m0, m1), fmaxf(m2, m3));
  m = fmaxf(m, __shfl_xor(m, 8, 64));
  m = fmaxf(m, __shfl_xor(m, 16, 64));
  m = fmaxf(m, __shfl_xor(m, 32, 64));
  float s0 = 0.0f, s1 = 0.0f, s2 = 0.0f, s3 = 0.0f;
#pragma unroll
  for (int i = 0; i < 128; i += 4) {
    s0 += fexp2(u[i] - m);
    s1 += fexp2(u[i + 1] - m);
    s2 += fexp2(u[i + 2] - m);
    s3 += fexp2(u[i + 3] - m);
  }
  float s = (s0 + s1) + (s2 + s3);
  s += __shfl_xor(s, 8, 64);
  s += __shfl_xor(s, 16, 64);
  s += __shfl_xor(s, 32, 64);
  if (lane < 8) {
    float F2 = fmaf(K2E, x2, -LOG2S) - m - flog2(s);
    xpackF[row] = make_float4(x.x, x.y, x2, F2);
  }
}

// g: block bid handles 16 cols; wave = 4 cols x 16 chunks, 128 rows/lane.
__device__ __forceinline__ void g_body(int bid, int t, float4* sh,
    const float4* __restrict__ xpackF, const float* __restrict__ pos,
    const float* __restrict__ logb2, float4* __restrict__ ypackG) {
  int bb = bid >> 6;
  const float4* xsrc = xpackF + (bb << 11);
#pragma unroll
  for (int k = 0; k < 8; ++k) {
    int e = t + (k << 8);
    float4 x = xsrc[e];
    sh[e + (e >> 7)] = make_float4(x.x, x.y, fmaf(-K2E, x.z, x.w), 0.0f);
  }
  __syncthreads();
  int w = t >> 6, lane = t & 63;
  int r = lane & 3, chunk = lane >> 2;
  int col = (bid << 4) + (w << 2) + r;
  float2 y = ((const float2*)pos)[col];
  float y2 = y.x * y.x + y.y * y.y;
  float ky0 = TWOK * y.x, ky1 = TWOK * y.y;
  const float4* cb = sh + chunk * 129;
  float u[128];
  float m0 = -3.4e38f, m1 = m0, m2 = m0, m3 = m0;
#pragma unroll
  for (int i = 0; i < 128; i += 4) {
    float4 a0 = cb[i], a1 = cb[i + 1], a2 = cb[i + 2], a3 = cb[i + 3];
    float u0 = fmaf(ky0, a0.x, fmaf(ky1, a0.y, a0.z));
    float u1 = fmaf(ky0, a1.x, fmaf(ky1, a1.y, a1.z));
    float u2 = fmaf(ky0, a2.x, fmaf(ky1, a2.y, a2.z));
    float u3 = fmaf(ky0, a3.x, fmaf(ky1, a3.y, a3.z));
    u[i] = u0; u[i + 1] = u1; u[i + 2] = u2; u[i + 3] = u3;
    m0 = fmaxf(m0, u0); m1 = fmaxf(m1, u1);
    m2 = fmaxf(m2, u2); m3 = fmaxf(m3, u3);
  }
  float m = fmaxf(fmaxf(m0, m1), fmaxf(m2, m3));
  m = fmaxf(m, __shfl_xor(m, 4, 64));
  m = fmaxf(m, __shfl_xor(m, 8, 64));
  m = fmaxf(m, __shfl_xor(m, 16, 64));
  m = fmaxf(m, __shfl_xor(m, 32, 64));
  float s0 = 0.0f, s1 = 0.0f, s2 = 0.0f, s3 = 0.0f;
#pragma unroll
  for (int i = 0; i < 128; i += 4) {
    s0 += fexp2(u[i] - m);
    s1 += fexp2(u[i + 1] - m);
    s2 += fexp2(u[i + 2] - m);
    s3 += fexp2(u[i + 3] - m);
  }
  float s = (s0 + s1) + (s2 + s3);
  s += __shfl_xor(s, 4, 64);
  s += __shfl_xor(s, 8, 64);
  s += __shfl_xor(s, 16, 64);
  s += __shfl_xor(s, 32, 64);
  if (lane < 4) {
    float G2 = fmaf(K2E, y2, logb2[col]) - m - flog2(s);
    ypackG[col] = make_float4(y.x, y.y, y2, G2);
  }
}

// setup for one batch b (256 threads): histogram -> logb2, init ypackG.
__device__ __forceinline__ void setup_body(int b, int t, float4* sh,
    const int* __restrict__ labels, const float* __restrict__ pos,
    float4* __restrict__ ypackG, float* __restrict__ logb2) {
  int* cnt = (int*)sh;
#pragma unroll
  for (int k = 0; k < 4; ++k) cnt[t + (k << 8)] = 0;
  __syncthreads();
#pragma unroll
  for (int k = 0; k < 8; ++k)
    atomicAdd(&cnt[labels[(b << 11) + t + (k << 8)] & (PP - 1)], 1);
  __syncthreads();
#pragma unroll
  for (int k = 0; k < 4; ++k) {
    int p = t + (k << 8);
    int c = cnt[p];
    logb2[(b << 10) + p] = (c > 0) ? (flog2((float)c) - LOG2S) : NEG_INF;
    float2 y = ((const float2*)pos)[(b << 10) + p];
    ypackG[(b << 10) + p] = make_float4(y.x, y.y, y.x * y.x + y.y * y.y, 0.0f);
  }
}

// final: block bid -> waves handle 8 rows each; partial[bid] = block sum.
__device__ __forceinline__ void final_body(int bid, int t, float4* sh,
    const float4* __restrict__ ypackG, const float4* __restrict__ xpackF,
    float* __restrict__ partial) {
  int w = t >> 6, lane = t & 63;
  int wg = (bid << 2) + w;  // 0..2047
  float wtot = 0.0f;
#pragma unroll
  for (int r = 0; r < 8; ++r) {
    int row = (wg << 3) + r;  // 0..16383
    int b = row >> 11;
    float4 x = xpackF[row];  // broadcast load
    const float4* yp = ypackG + (b << 10);
    float sum = 0.0f;
#pragma unroll
    for (int i = 0; i < 16; ++i) {
      float4 y = yp[(i << 6) + lane];
      float tt = fmaf(x.y, y.y, x.x * y.x);
      float c = fmaxf(fmaf(-2.0f, tt, x.z + y.z), 0.0f);
      float v2 = fmaf(-K2E, c, x.w + y.w);
      sum = fmaf(fexp2(v2), c, sum);
    }
#pragma unroll
    for (int off = 32; off; off >>= 1) sum += __shfl_xor(sum, off, 64);
    wtot += sum;
  }
  float* shf = (float*)sh;
  if (lane == 0) shf[w] = wtot;
  __syncthreads();
  if (t == 0) partial[bid] = (shf[0] + shf[1]) + (shf[2] + shf[3]);
}

// ---- the persistent cooperative kernel ----
__global__ __launch_bounds__(256, 2) void sinkhorn_all(
    const float* __restrict__ preds, const int* __restrict__ labels,
    const float* __restrict__ pos, float* __restrict__ out,
    float4* __restrict__ ypackG, float4* __restrict__ xpackF,
    float* __restrict__ logb2, float* __restrict__ partial) {
  __shared__ float4 sh[2064];  // 33 KB: fits g staging; reused everywhere
  cg::grid_group grid = cg::this_grid();
  int bid = blockIdx.x, t = threadIdx.x;

  if (bid < BB) setup_body(bid, t, sh, labels, pos, ypackG, logb2);
  grid.sync();

  for (int it = 0; it < ITERS; ++it) {
    f_body(bid, t, sh, ypackG, preds, xpackF);
    grid.sync();
    g_body(bid, t, sh, xpackF, pos, logb2, ypackG);
    grid.sync();
  }

  final_body(bid, t, sh, ypackG, xpackF, partial);
  grid.sync();

  if (bid == 0) {
    float* shf = (float*)sh;
    shf[t] = partial[t] + partial[t + 256];
    __syncthreads();
    for (int k = 128; k; k >>= 1) {
      if (t < k) shf[t] += shf[t + k];
      __syncthreads();
    }
    if (t == 0) out[0] = shf[0] * (1.0f / (float)BB);
  }
}

// ---- fallback multi-launch kernels (used only if cooperative launch fails) ----
__global__ __launch_bounds__(256) void setup_k(const int* __restrict__ labels,
    const float* __restrict__ pos, float4* __restrict__ ypackG,
    float* __restrict__ logb2) {
  __shared__ float4 sh[1024];
  setup_body(blockIdx.x, threadIdx.x, sh, labels, pos, ypackG, logb2);
}
__global__ __launch_bounds__(256, 2) void f_k(const float4* __restrict__ ypackG,
    const float* __restrict__ preds, float4* __restrict__ xpackF) {
  __shared__ float4 sh[1032];
  f_body(blockIdx.x, threadIdx.x, sh, ypackG, preds, xpackF);
}
__global__ __launch_bounds__(256, 2) void g_k(const float4* __restrict__ xpackF,
    const float* __restrict__ pos, const float* __restrict__ logb2,
    float4* __restrict__ ypackG) {
  __shared__ float4 sh[2064];
  g_body(blockIdx.x, threadIdx.x, sh, xpackF, pos, logb2, ypackG);
}
__global__ __launch_bounds__(256) void final_k(const float4* __restrict__ ypackG,
    const float4* __restrict__ xpackF, float* __restrict__ partial) {
  __shared__ float4 sh[4];
  final_body(blockIdx.x, threadIdx.x, sh, ypackG, xpackF, partial);
}
__global__ __launch_bounds__(256) void reduce_k(const float* __restrict__ partial,
    float* __restrict__ out) {
  __shared__ float shf[256];
  int t = threadIdx.x;
  shf[t] = partial[t] + partial[t + 256];
  __syncthreads();
  for (int k = 128; k; k >>= 1) {
    if (t < k) shf[t] += shf[t + k];
    __syncthreads();
  }
  if (t == 0) out[0] = shf[0] * (1.0f / (float)BB);
}

extern "C" void kernel_launch(void* const* d_in, const int* in_sizes, int n_in,
                              void* d_out, int out_size, void* d_ws, size_t ws_size,
                              hipStream_t stream) {
  const float* preds = (const float*)d_in[0];   // [B,S,2]
  const int* labels = (const int*)d_in[1];      // [B,S]
  const float* pos = (const float*)d_in[2];     // [B,P,2]
  float* out = (float*)d_out;
  char* ws = (char*)d_ws;
  float4* ypackG = (float4*)(ws);
  float4* xpackF = (float4*)(ws + 131072);
  float* logb2 = (float*)(ws + 393216);
  float* partial = (float*)(ws + 425984);  // 512 floats

  void* args[] = {(void*)&preds, (void*)&labels, (void*)&pos, (void*)&out,
                  (void*)&ypackG, (void*)&xpackF, (void*)&logb2, (void*)&partial};
  hipError_t e = hipLaunchCooperativeKernel((const void*)sinkhorn_all,
                                            dim3(512), dim3(256), args, 0, stream);
  if (e != hipSuccess) {
    // fallback: multi-launch path (identical math)
    hipLaunchKernelGGL(setup_k, dim3(BB), dim3(256), 0, stream,
                       labels, pos, ypackG, logb2);
    for (int it = 0; it < ITERS; ++it) {
      hipLaunchKernelGGL(f_k, dim3(512), dim3(256), 0, stream,
                         ypackG, preds, xpackF);
      hipLaunchKernelGGL(g_k, dim3(512), dim3(256), 0, stream,
                         xpackF, pos, logb2, ypackG);
    }
    hipLaunchKernelGGL(final_k, dim3(512), dim3(256), 0, stream,
                       ypackG, xpackF, partial);
    hipLaunchKernelGGL(reduce_k, dim3(1), dim3(256), 0, stream, partial, out);
  }
}

// Round 4
// 1102.660 us; speedup vs baseline: 4.8200x; 4.8200x over previous
//
#include <hip/hip_runtime.h>
#include <math.h>

// Sinkhorn loss, B=8, S=2048, P=1024, D=2, eps=0.01, 50 iters.
// Persistent cooperative kernel, but with CUSTOM per-batch barriers:
//  - cross-block data (potentials F2/G2, logb2, partials) exchanged ONLY via
//    agent-scope relaxed atomics (sc1: bypass non-coherent L1/L2, hit IC)
//  - barrier = syncthreads (drains stores via its vmcnt(0)) + relaxed
//    atomicAdd + s_sleep spin. NO buffer_wbl2/buffer_inv (that was the
//    52us/sync cost of cg::grid.sync in round 3).
//  - batches are independent: 8 counters x 64 arrivals each.
// Base-2 scaled potentials: F2 = f/(eps*ln2), G2 = g/(eps*ln2).
//   u(s,p) = 2K(x.y) + q,  q = G2[p] - K*y2  (row-const -K*x2 folds out)

#define BB 8
#define SS 2048
#define PP 1024
#define NEG_INF -1e9f
#define LOG2S 11.0f
#define ITERS 50
#define K2E 144.269504088896f   /* 100*log2(e) */
#define TWOK 288.539008177792f  /* 200*log2(e) */

__device__ __forceinline__ float fexp2(float x) { return __builtin_amdgcn_exp2f(x); }
__device__ __forceinline__ float flog2(float x) { return __builtin_amdgcn_logf(x); }
__device__ __forceinline__ float aload(const float* p) {
  return __hip_atomic_load(p, __ATOMIC_RELAXED, __HIP_MEMORY_SCOPE_AGENT);
}
__device__ __forceinline__ void astore(float* p, float v) {
  __hip_atomic_store(p, v, __ATOMIC_RELAXED, __HIP_MEMORY_SCOPE_AGENT);
}

// 64-arrival per-batch barrier. Entry __syncthreads() emits
// s_waitcnt vmcnt(0) -> all prior agent (sc1) stores are globally visible
// before lane0's arrival atomic.
__device__ __forceinline__ void batch_barrier(unsigned* ctr, unsigned target) {
  __syncthreads();
  if (threadIdx.x == 0) {
    __hip_atomic_fetch_add(ctr, 1u, __ATOMIC_RELAXED, __HIP_MEMORY_SCOPE_AGENT);
    while (__hip_atomic_load(ctr, __ATOMIC_RELAXED, __HIP_MEMORY_SCOPE_AGENT) < target)
      __builtin_amdgcn_s_sleep(1);
  }
  __syncthreads();
}

// f: block handles 32 rows; wave = 8 rows x 8 chunks, 128 cols/lane.
template <bool FIRST>
__device__ __forceinline__ void f_phase(int bid, int t, float4* sh,
    const float* __restrict__ G2, const float* __restrict__ pos,
    const float* __restrict__ preds, float* __restrict__ F2) {
  int bb = bid >> 6;
  const float2* ysrc = (const float2*)pos + (bb << 10);
  const float* g2b = G2 + (bb << 10);
#pragma unroll
  for (int k = 0; k < 4; ++k) {
    int e = t + (k << 8);
    float2 y = ysrc[e];  // cached load: pristine input, never stale
    float g = FIRST ? 0.0f : aload(g2b + e);  // agent: cross-XCD fresh
    sh[e + (e >> 7)] = make_float4(y.x, y.y, fmaf(-K2E, fmaf(y.x, y.x, y.y * y.y), g), 0.0f);
  }
  __syncthreads();
  int w = t >> 6, lane = t & 63;
  int r = lane & 7, chunk = lane >> 3;
  int row = (bid << 5) + (w << 3) + r;
  float2 x = ((const float2*)preds)[row];
  float x2 = fmaf(x.x, x.x, x.y * x.y);
  float kx0 = TWOK * x.x, kx1 = TWOK * x.y;
  const float4* cb = sh + chunk * 129;
  float u[128];
  float m0 = -3.4e38f, m1 = m0, m2 = m0, m3 = m0;
#pragma unroll
  for (int i = 0; i < 128; i += 4) {
    float4 a0 = cb[i], a1 = cb[i + 1], a2 = cb[i + 2], a3 = cb[i + 3];
    float u0 = fmaf(kx0, a0.x, fmaf(kx1, a0.y, a0.z));
    float u1 = fmaf(kx0, a1.x, fmaf(kx1, a1.y, a1.z));
    float u2 = fmaf(kx0, a2.x, fmaf(kx1, a2.y, a2.z));
    float u3 = fmaf(kx0, a3.x, fmaf(kx1, a3.y, a3.z));
    u[i] = u0; u[i + 1] = u1; u[i + 2] = u2; u[i + 3] = u3;
    m0 = fmaxf(m0, u0); m1 = fmaxf(m1, u1);
    m2 = fmaxf(m2, u2); m3 = fmaxf(m3, u3);
  }
  float m = fmaxf(fmaxf(m0, m1), fmaxf(m2, m3));
  m = fmaxf(m, __shfl_xor(m, 8, 64));
  m = fmaxf(m, __shfl_xor(m, 16, 64));
  m = fmaxf(m, __shfl_xor(m, 32, 64));
  float s0 = 0.0f, s1 = 0.0f, s2 = 0.0f, s3 = 0.0f;
#pragma unroll
  for (int i = 0; i < 128; i += 4) {
    s0 += fexp2(u[i] - m);
    s1 += fexp2(u[i + 1] - m);
    s2 += fexp2(u[i + 2] - m);
    s3 += fexp2(u[i + 3] - m);
  }
  float s = (s0 + s1) + (s2 + s3);
  s += __shfl_xor(s, 8, 64);
  s += __shfl_xor(s, 16, 64);
  s += __shfl_xor(s, 32, 64);
  if (lane < 8) {
    float F2v = fmaf(K2E, x2, -LOG2S) - m - flog2(s);
    astore(F2 + row, F2v);
  }
}

// g: block handles 16 cols; wave = 4 cols x 16 chunks, 128 rows/lane.
__device__ __forceinline__ void g_phase(int bid, int t, float4* sh,
    const float* __restrict__ F2, const float* __restrict__ pos,
    const float* __restrict__ preds, const float* __restrict__ logb2,
    float* __restrict__ G2) {
  int bb = bid >> 6;
  const float2* xsrc = (const float2*)preds + (bb << 11);
  const float* f2b = F2 + (bb << 11);
#pragma unroll
  for (int k = 0; k < 8; ++k) {
    int e = t + (k << 8);
    float2 x = xsrc[e];
    float f = aload(f2b + e);
    sh[e + (e >> 7)] = make_float4(x.x, x.y, fmaf(-K2E, fmaf(x.x, x.x, x.y * x.y), f), 0.0f);
  }
  __syncthreads();
  int w = t >> 6, lane = t & 63;
  int r = lane & 3, chunk = lane >> 2;
  int col = (bid << 4) + (w << 2) + r;
  float2 y = ((const float2*)pos)[col];
  float y2 = fmaf(y.x, y.x, y.y * y.y);
  float ky0 = TWOK * y.x, ky1 = TWOK * y.y;
  const float4* cb = sh + chunk * 129;
  float u[128];
  float m0 = -3.4e38f, m1 = m0, m2 = m0, m3 = m0;
#pragma unroll
  for (int i = 0; i < 128; i += 4) {
    float4 a0 = cb[i], a1 = cb[i + 1], a2 = cb[i + 2], a3 = cb[i + 3];
    float u0 = fmaf(ky0, a0.x, fmaf(ky1, a0.y, a0.z));
    float u1 = fmaf(ky0, a1.x, fmaf(ky1, a1.y, a1.z));
    float u2 = fmaf(ky0, a2.x, fmaf(ky1, a2.y, a2.z));
    float u3 = fmaf(ky0, a3.x, fmaf(ky1, a3.y, a3.z));
    u[i] = u0; u[i + 1] = u1; u[i + 2] = u2; u[i + 3] = u3;
    m0 = fmaxf(m0, u0); m1 = fmaxf(m1, u1);
    m2 = fmaxf(m2, u2); m3 = fmaxf(m3, u3);
  }
  float m = fmaxf(fmaxf(m0, m1), fmaxf(m2, m3));
  m = fmaxf(m, __shfl_xor(m, 4, 64));
  m = fmaxf(m, __shfl_xor(m, 8, 64));
  m = fmaxf(m, __shfl_xor(m, 16, 64));
  m = fmaxf(m, __shfl_xor(m, 32, 64));
  float s0 = 0.0f, s1 = 0.0f, s2 = 0.0f, s3 = 0.0f;
#pragma unroll
  for (int i = 0; i < 128; i += 4) {
    s0 += fexp2(u[i] - m);
    s1 += fexp2(u[i + 1] - m);
    s2 += fexp2(u[i + 2] - m);
    s3 += fexp2(u[i + 3] - m);
  }
  float s = (s0 + s1) + (s2 + s3);
  s += __shfl_xor(s, 4, 64);
  s += __shfl_xor(s, 8, 64);
  s += __shfl_xor(s, 16, 64);
  s += __shfl_xor(s, 32, 64);
  if (lane < 4) {
    float G2v = fmaf(K2E, y2, aload(logb2 + col)) - m - flog2(s);
    astore(G2 + col, G2v);
  }
}

__global__ __launch_bounds__(256, 2) void sinkhorn_all(
    const float* __restrict__ preds, const int* __restrict__ labels,
    const float* __restrict__ pos, float* __restrict__ out,
    float* __restrict__ G2, float* __restrict__ F2,
    float* __restrict__ logb2, float* __restrict__ partial,
    float* __restrict__ battot, unsigned* __restrict__ bar) {
  __shared__ float4 sh[2064];  // 33 KB
  const int bid = blockIdx.x, t = threadIdx.x;
  const int bb = bid >> 6;
  unsigned* myctr = bar + bb * 16;   // 64B-strided per-batch counters
  unsigned* gctr = bar + 8 * 16;
  unsigned target = 0;

  // ---- f iteration 0 (G2 == 0 analytically; no G2 read) ----
  f_phase<true>(bid, t, sh, G2, pos, preds, F2);
  // batch-leader block also builds label histogram -> logb2 (concurrent w/ f0)
  if ((bid & 63) == 0) {
    int* cnt = (int*)(sh + 1040);  // region beyond f staging (1032 float4s)
#pragma unroll
    for (int k = 0; k < 4; ++k) cnt[t + (k << 8)] = 0;
    __syncthreads();
#pragma unroll
    for (int k = 0; k < 8; ++k)
      atomicAdd(&cnt[labels[(bb << 11) + t + (k << 8)] & (PP - 1)], 1);
    __syncthreads();
#pragma unroll
    for (int k = 0; k < 4; ++k) {
      int p = t + (k << 8);
      int c = cnt[p];
      astore(logb2 + (bb << 10) + p, (c > 0) ? (flog2((float)c) - LOG2S) : NEG_INF);
    }
  }
  target += 64; batch_barrier(myctr, target);

  for (int it = 0;; ++it) {
    g_phase(bid, t, sh, F2, pos, preds, logb2, G2);
    target += 64; batch_barrier(myctr, target);
    if (it == ITERS - 1) break;
    f_phase<false>(bid, t, sh, G2, pos, preds, F2);
    target += 64; batch_barrier(myctr, target);
  }

  // ---- final: block sum of sum_p exp2(-K*C + F2 + G2) * C over its 32 rows
  {
    int w = t >> 6, lane = t & 63;
    const float2* pos2 = (const float2*)pos + (bb << 10);
    const float* g2b = G2 + (bb << 10);
    float wtot = 0.0f;
#pragma unroll
    for (int rr = 0; rr < 8; ++rr) {
      int row = (bid << 5) + (w << 3) + rr;
      float2 x = ((const float2*)preds)[row];  // broadcast cached
      float Fv = aload(F2 + row);              // broadcast agent
      float x2 = fmaf(x.x, x.x, x.y * x.y);
      float sum = 0.0f;
#pragma unroll
      for (int i = 0; i < 16; ++i) {
        float2 y = pos2[(i << 6) + lane];
        float Gv = aload(g2b + (i << 6) + lane);
        float y2 = fmaf(y.x, y.x, y.y * y.y);
        float tt = fmaf(x.y, y.y, x.x * y.x);
        float c = fmaxf(fmaf(-2.0f, tt, x2 + y2), 0.0f);
        float v2 = fmaf(-K2E, c, Fv + Gv);
        sum = fmaf(fexp2(v2), c, sum);
      }
#pragma unroll
      for (int off = 32; off; off >>= 1) sum += __shfl_xor(sum, off, 64);
      wtot += sum;
    }
    float* shf = (float*)sh;
    __syncthreads();
    if (lane == 0) shf[w] = wtot;
    __syncthreads();
    if (t == 0) astore(partial + bid, (shf[0] + shf[1]) + (shf[2] + shf[3]));
  }
  target += 64; batch_barrier(myctr, target);

  // ---- leader block per batch: deterministic 64-partial reduce ----
  if ((bid & 63) == 0 && t < 64) {
    float pv = aload(partial + (bb << 6) + t);
#pragma unroll
    for (int off = 32; off; off >>= 1) pv += __shfl_xor(pv, off, 64);
    if (t == 0) {
      astore(battot + bb, pv);
      __builtin_amdgcn_s_waitcnt(0);  // battot visible before arrival
      __hip_atomic_fetch_add(gctr, 1u, __ATOMIC_RELAXED, __HIP_MEMORY_SCOPE_AGENT);
      if (bid == 0) {
        while (__hip_atomic_load(gctr, __ATOMIC_RELAXED, __HIP_MEMORY_SCOPE_AGENT) < 8u)
          __builtin_amdgcn_s_sleep(1);
        float tot = 0.0f;
#pragma unroll
        for (int i = 0; i < 8; ++i) tot += aload(battot + i);
        out[0] = tot * 0.125f;
      }
    }
  }
}

extern "C" void kernel_launch(void* const* d_in, const int* in_sizes, int n_in,
                              void* d_out, int out_size, void* d_ws, size_t ws_size,
                              hipStream_t stream) {
  const float* preds = (const float*)d_in[0];   // [B,S,2]
  const int* labels = (const int*)d_in[1];      // [B,S]
  const float* pos = (const float*)d_in[2];     // [B,P,2]
  float* out = (float*)d_out;
  char* ws = (char*)d_ws;
  // ws layout
  unsigned* bar = (unsigned*)(ws);              // [0, 1024)
  float* G2 = (float*)(ws + 1024);              // B*P floats
  float* F2 = (float*)(ws + 33792);             // B*S floats
  float* logb2 = (float*)(ws + 99328);          // B*P floats
  float* partial = (float*)(ws + 132096);       // 512 floats
  float* battot = (float*)(ws + 134144);        // 8 floats

  hipMemsetAsync(bar, 0, 1024, stream);  // zero barrier counters (capturable)

  void* args[] = {(void*)&preds, (void*)&labels, (void*)&pos, (void*)&out,
                  (void*)&G2, (void*)&F2, (void*)&logb2, (void*)&partial,
                  (void*)&battot, (void*)&bar};
  hipError_t e = hipLaunchCooperativeKernel((const void*)sinkhorn_all,
                                            dim3(512), dim3(256), args, 0, stream);
  if (e != hipSuccess) {
    // plain launch: 512 blocks x 256 thr at 2 blocks/CU == exact device
    // capacity -> co-resident in practice.
    hipLaunchKernelGGL(sinkhorn_all, dim3(512), dim3(256), 0, stream,
                       preds, labels, pos, out, G2, F2, logb2, partial,
                       battot, bar);
  }
}